// Round 3
// baseline (50.079 us; speedup 1.0000x reference)
//
#include <hip/hip_runtime.h>

// PGA G(3,0,1) geometric product, pairwise: out[n,m,:] = T[n] * reverse(T[m]).
// R2: halve VALU issue via v_pk_fma_f32. Outputs/operands packed in float2
// pairs by the e1 generator bit; XOR structure of the gp table guarantees each
// packed term reads one packed a-source (with compile-time swap/sign -> VOP3P
// op_sel / neg modifiers). Store path (LDS transpose -> coalesced dwordx4)
// unchanged from R1.

namespace {

typedef float f2 __attribute__((ext_vector_type(2)));

constexpr int popcount4(unsigned x) {
    int c = 0;
    for (int i = 0; i < 5; ++i) c += (x >> i) & 1;
    return c;
}

struct GPTab {
    signed char sgn[16][16];   // sign of e_j * e_k (rev on k folded in); 0 if vanishes
    unsigned char idx[16][16]; // output blade index of e_j * e_k
};

// Blade bitmasks in the reference's basis order:
// (), e0..e3, e01,e02,e03,e12,e13,e23, e012,e013,e023,e123, e0123
constexpr unsigned MASKV[16] = {0u, 1u, 2u, 4u, 8u,
                                3u, 5u, 9u, 6u, 10u, 12u,
                                7u, 11u, 13u, 14u, 15u};

constexpr GPTab make_tab() {
    GPTab t{};
    int inv[16] = {};
    for (int i = 0; i < 16; ++i) inv[(int)MASKV[i]] = i;

    for (int j = 0; j < 16; ++j) {
        for (int k = 0; k < 16; ++k) {
            unsigned a = MASKV[j], b = MASKV[k];
            if (a & b & 1u) {            // shared e0 -> e0^2 = 0
                t.sgn[j][k] = 0;
                t.idx[j][k] = 0;
                continue;
            }
            int swaps = 0;
            for (int g = 0; g < 4; ++g)
                if ((b >> g) & 1u)
                    swaps += popcount4(a >> (g + 1));
            int s = (swaps & 1) ? -1 : 1;
            int r = popcount4(b);
            if ((r * (r - 1) / 2) & 1) s = -s;   // reverse() sign on 2nd operand
            t.sgn[j][k] = (signed char)s;
            t.idx[j][k] = (unsigned char)inv[(int)(a ^ b)];
        }
    }
    return t;
}

constexpr GPTab TAB = make_tab();

// Packing of the 16 blades into 8 float2 slots, paired by the e1 bit (mask^2).
// Pairs are e0-homogeneous, so for every k either both halves of a slot
// receive a term or neither does (96 pk_fma total).
struct Packing {
    unsigned char pl[8], ph[8];      // blade index of lo/hi member of slot
    unsigned char slot[16], half[16];
    signed char   act[16][8];        // does slot t receive terms for this k?
    unsigned char src[16][8];        // source a-slot
    unsigned char swp[16][8];        // lo output needs hi of source?
    signed char   s0[16][8], s1[16][8];
};

constexpr Packing make_packing() {
    Packing p{};
    int inv[16] = {};
    for (int i = 0; i < 16; ++i) inv[(int)MASKV[i]] = i;

    int t = 0;
    for (int e0bit = 0; e0bit <= 1; ++e0bit) {
        for (unsigned m = 0; m < 16; ++m) {
            if ((m & 2u) == 0u && (int)(m & 1u) == e0bit) {
                int lo = inv[(int)m], hi = inv[(int)(m | 2u)];
                p.pl[t] = (unsigned char)lo;
                p.ph[t] = (unsigned char)hi;
                p.slot[lo] = (unsigned char)t; p.half[lo] = 0;
                p.slot[hi] = (unsigned char)t; p.half[hi] = 1;
                ++t;
            }
        }
    }

    GPTab tab = make_tab();
    for (int k = 0; k < 16; ++k) {
        for (int s = 0; s < 8; ++s) {
            int i0 = p.pl[s], i1 = p.ph[s];
            int j0 = inv[(int)(MASKV[i0] ^ MASKV[k])];
            int j1 = inv[(int)(MASKV[i1] ^ MASKV[k])];
            int g0 = tab.sgn[j0][k], g1 = tab.sgn[j1][k];
            p.act[k][s] = (signed char)(g0 != 0);
            p.src[k][s] = p.slot[j0];
            p.swp[k][s] = p.half[j0];        // j1 is the other half of same slot
            p.s0[k][s] = (signed char)g0;
            p.s1[k][s] = (signed char)g1;
        }
    }
    return p;
}

constexpr Packing PK = make_packing();

} // namespace

// Tt[j*nrows + m] = T[m*16 + j]   (component-major copy, 128 KB)
__global__ __launch_bounds__(256) void transpose_kernel(
    const float* __restrict__ T, float* __restrict__ Tt, int nrows) {
    int t = blockIdx.x * 256 + threadIdx.x;
    if (t < nrows * 16) {
        int m = t >> 4, j = t & 15;
        Tt[j * nrows + m] = T[t];
    }
}

template <bool USE_TT>
__global__ __launch_bounds__(256) void gp_pairs_kernel(
    const float* __restrict__ T, const float* __restrict__ Tt,
    float* __restrict__ out, int nrows) {
    const int lane = threadIdx.x & 63;
    const int wave = threadIdx.x >> 6;
    const int m = blockIdx.x * 256 + (int)threadIdx.x;
    const int n = blockIdx.y;                 // wave-uniform
    const int mc = (m < nrows) ? m : (nrows - 1);

    // 64 pairs/wave, 20-float padded stride (80 B, 16B-aligned) per pair.
    __shared__ float lds[4][64 * 20];

    float a[16], b[16];
#pragma unroll
    for (int q = 0; q < 4; ++q) {             // uniform address -> broadcast
        float4 va = reinterpret_cast<const float4*>(T)[(size_t)n * 4 + q];
        a[q * 4 + 0] = va.x; a[q * 4 + 1] = va.y;
        a[q * 4 + 2] = va.z; a[q * 4 + 3] = va.w;
    }
    if constexpr (USE_TT) {
#pragma unroll
        for (int j = 0; j < 16; ++j)          // fully coalesced: lane i -> +4B
            b[j] = Tt[(size_t)j * nrows + mc];
    } else {
#pragma unroll
        for (int q = 0; q < 4; ++q) {
            float4 vb = reinterpret_cast<const float4*>(T)[(size_t)mc * 4 + q];
            b[q * 4 + 0] = vb.x; b[q * 4 + 1] = vb.y;
            b[q * 4 + 2] = vb.z; b[q * 4 + 3] = vb.w;
        }
    }

    // Pack a into e1-paired float2 slots.
    f2 A[8];
#pragma unroll
    for (int s = 0; s < 8; ++s) {
        f2 v; v.x = a[PK.pl[s]]; v.y = a[PK.ph[s]];
        A[s] = v;
    }

    f2 O[8];
#pragma unroll
    for (int s = 0; s < 8; ++s) O[s] = (f2)(0.0f);

#pragma unroll
    for (int k = 0; k < 16; ++k) {
        const float bk = b[k];
        f2 bb; bb.x = bk; bb.y = bk;
#pragma unroll
        for (int s = 0; s < 8; ++s) {
            if (PK.act[k][s]) {               // compile-time after unroll
                const f2 srcv = A[PK.src[k][s]];
                float x = PK.swp[k][s] ? srcv.y : srcv.x;
                float y = PK.swp[k][s] ? srcv.x : srcv.y;
                if (PK.s0[k][s] < 0) x = -x;  // -> neg_lo
                if (PK.s1[k][s] < 0) y = -y;  // -> neg_hi
                f2 av; av.x = x; av.y = y;
                O[s] = __builtin_elementwise_fma(av, bb, O[s]);
            }
        }
    }

    // Unpack to natural blade order.
    float o[16];
#pragma unroll
    for (int i = 0; i < 16; ++i)
        o[i] = PK.half[i] ? O[PK.slot[i]].y : O[PK.slot[i]].x;

    // Stage this wave's 64x16 output tile in LDS (padded), then store coalesced.
    float* w = &lds[wave][lane * 20];
#pragma unroll
    for (int q = 0; q < 4; ++q)
        *reinterpret_cast<float4*>(w + q * 4) =
            make_float4(o[q * 4 + 0], o[q * 4 + 1], o[q * 4 + 2], o[q * 4 + 3]);

    __syncthreads();

    const int waveM0 = blockIdx.x * 256 + wave * 64;
    float4* __restrict__ ov =
        reinterpret_cast<float4*>(out) + ((size_t)n * nrows + waveM0) * 4;
#pragma unroll
    for (int q = 0; q < 4; ++q) {
        const int g = q * 64 + lane;          // float4 index within wave tile
        const int p = g >> 2;                 // pair within wave
        const int c = g & 3;                  // float4 chunk within pair
        if (waveM0 + p < nrows) {
            ov[g] = *reinterpret_cast<const float4*>(&lds[wave][p * 20 + c * 4]);
        }
    }
}

extern "C" void kernel_launch(void* const* d_in, const int* in_sizes, int n_in,
                              void* d_out, int out_size, void* d_ws, size_t ws_size,
                              hipStream_t stream) {
    const float* T = (const float*)d_in[0];
    float* out = (float*)d_out;
    const int nrows = in_sizes[0] / 16;       // 2048
    const size_t tt_bytes = (size_t)nrows * 16 * sizeof(float);

    dim3 grid((unsigned)((nrows + 255) / 256), (unsigned)nrows, 1);

    if (ws_size >= tt_bytes) {
        float* Tt = (float*)d_ws;
        transpose_kernel<<<(nrows * 16 + 255) / 256, 256, 0, stream>>>(T, Tt, nrows);
        gp_pairs_kernel<true><<<grid, 256, 0, stream>>>(T, Tt, out, nrows);
    } else {
        gp_pairs_kernel<false><<<grid, 256, 0, stream>>>(T, nullptr, out, nrows);
    }
}